// Round 12
// baseline (658.179 us; speedup 1.0000x reference)
//
#include <hip/hip_runtime.h>
#include <hip/hip_bf16.h>

typedef unsigned short u16;
typedef __bf16 bf16x8 __attribute__((ext_vector_type(8)));
typedef float f32x4 __attribute__((ext_vector_type(4)));

__device__ __forceinline__ float bf2f(u16 u) {
    unsigned v = ((unsigned)u) << 16;
    return __builtin_bit_cast(float, v);
}
__device__ __forceinline__ u16 f2bf(float f) {
    unsigned x = __builtin_bit_cast(unsigned, f);
    unsigned r = x + (0x7fffu + ((x >> 16) & 1u));   // RNE
    return (u16)(r >> 16);
}
__device__ __forceinline__ void gload16(const void* g, void* l) {
    __builtin_amdgcn_global_load_lds(
        (const __attribute__((address_space(1))) void*)g,
        (__attribute__((address_space(3))) void*)l, 16, 0, 0);
}

// ---------------- weight transpose+convert: fp32 [K][N] -> bf16 [N][K] -------
__global__ __launch_bounds__(256) void transpose_w(const float* __restrict__ src,
    u16* __restrict__ dst, int K, int N)
{
    __shared__ u16 T[64][33];
    int k0 = blockIdx.x * 32, n0 = blockIdx.y * 64;
    int t = threadIdx.x;
    int nc = t & 63, krb = (t >> 6) * 8;
#pragma unroll
    for (int j = 0; j < 8; j++) {
        int kr = krb + j;
        T[nc][kr] = f2bf(src[(size_t)(k0 + kr) * N + n0 + nc]);
    }
    __syncthreads();
    int r = t >> 2, c0 = (t & 3) * 8;
    u16 tmp[8];
#pragma unroll
    for (int i = 0; i < 8; i++) tmp[i] = T[r][c0 + i];
    *(uint4*)&dst[(size_t)(n0 + r) * K + k0 + c0] = *(uint4*)tmp;
}

__global__ void zfill(u16* p) { p[threadIdx.x] = 0; }

__global__ __launch_bounds__(256) void cvt_bias(const float* __restrict__ s,
                                                u16* __restrict__ d, int n)
{
    int i = blockIdx.x * 256 + threadIdx.x;
    if (i < n) d[i] = f2bf(s[i]);
}

// ---- combined bias [sb | qkvb] (3584 fp32) ---------------------------------
__global__ __launch_bounds__(256) void concat_bias(const float* __restrict__ sb,
    const float* __restrict__ qkvb, float* __restrict__ cb)
{
    int i = blockIdx.x * 256 + threadIdx.x;
    if (i < 896) cb[i] = sb[i];
    else if (i < 3584) cb[i] = qkvb[i - 896];
}

// ---- qp boundary fill: entries whose 4 pool taps are all padded -> bq ------
__global__ __launch_bounds__(256) void qfill(const float* __restrict__ qkvb,
                                             u16* __restrict__ qp)
{
    int id = blockIdx.x * 256 + threadIdx.x;
    if (id >= 9800 * 112) return;
    int c8 = id % 112, rq = id / 112;
    int q = rq % 49, w = rq / 49;
    int qy = q / 7, qx = q - 7 * qy;
    int wh = (w / 5) % 5, ww = w % 5;
    if (!((wh == 4 && qy >= 4) || (ww == 4 && qx >= 4))) return;
    int c = c8 * 8;
    u16 o[8];
#pragma unroll
    for (int i = 0; i < 8; i++) o[i] = f2bf(qkvb[c + i]);
    *(uint4*)&qp[(size_t)rq * 896 + c] = *(uint4*)o;
}

// ---------------- LayerNorm: one wave per pixel (fp32 in, bf16 out) ----------
template<int C>
__global__ __launch_bounds__(256) void ln_kernel(const float* __restrict__ xf,
    const float* __restrict__ g, const float* __restrict__ b,
    u16* __restrict__ out, int npix)
{
    int wid = threadIdx.x >> 6, lane = threadIdx.x & 63;
    int pix = blockIdx.x * 4 + wid;
    if (pix >= npix) return;
    constexpr int J = C / 64;
    float v[J];
    float s = 0.f, s2 = 0.f;
#pragma unroll
    for (int j = 0; j < J; j++) {
        int c = lane + j * 64;
        float t = xf[(size_t)pix * C + c];
        v[j] = t; s += t; s2 += t * t;
    }
#pragma unroll
    for (int off = 32; off; off >>= 1) {
        s  += __shfl_xor(s,  off, 64);
        s2 += __shfl_xor(s2, off, 64);
    }
    float mean = s / C;
    float var = fmaxf(s2 / C - mean * mean, 0.f);
    float rs = rsqrtf(var + 1e-6f);
#pragma unroll
    for (int j = 0; j < J; j++) {
        int c = lane + j * 64;
        float o = (v[j] - mean) * rs * g[c] + b[c];
        out[(size_t)pix * C + c] = f2bf(o);
    }
}

// ---------------- BMx128 MFMA GEMM, BK=32, 2-buffer counted-vmcnt ------------
// Converged config (R4): BM=128 3-4 blk/CU; BM=256/8-phase/3-buffer all
// regressed — cross-block overlap hides the lockstep-phase latency. Mega rate
// (598 TF) is ~98.5% of the 2-phase structural ceiling (m233: 607 TF) — do
// not re-tune the schedule.
// EPI_MEGA (N=3584 = [skip|q|k|v]): bn<7 skip w/ fused 2x2 pool -> Yf fp32;
// bn 7-13 q w/ fused pool -> qp bf16 (every pixel pair is a valid window pool
// pair since WIN=14 even); bn 14-20 k -> kimg; bn 21-27 v -> vimg (both
// nontemporal: consumed by a later kernel, keep L2/L3 for A/B panels).
// EPI_PROJ (pixel space): Yf[gm] += val, M=8192 (ao written pixel-space by
// attn — windows disjoint, 16% padding FLOPs eliminated).
enum { EPI_GELU = 1, EPI_PROJ = 2, EPI_OUT = 3, EPI_MEGA = 6 };

template<int BM, int EPI, int SWZ>
__global__ __launch_bounds__(256, (BM == 64) ? 6 : 4) void gemm_t(
    const u16* __restrict__ A, const u16* __restrict__ BT,
    const u16* __restrict__ zrow, const float* __restrict__ bias,
    u16* __restrict__ Cb, u16* __restrict__ Cb2, u16* __restrict__ Cb3,
    float* __restrict__ Yf, float* __restrict__ Of,
    int M, int N, int K, int nbn)
{
    constexpr int MI = BM / 32;    // per-wave 16-row frags (wave covers BM/2)
    constexpr int PA = BM / 64;    // A staging units (256 thr x 16B = 4KB each)
    constexpr int ASZ = BM * 32, BSZ = 128 * 32;
    __shared__ __align__(16) u16 As[2][ASZ];
    __shared__ __align__(16) u16 Bs[2][BSZ];

    const int tid = threadIdx.x;
    int bm, bn;
    if (SWZ) {
        int nwg = gridDim.x, orig = blockIdx.x;
        int q = nwg >> 3, r = nwg & 7;
        int xcd = orig & 7, idx = orig >> 3;
        int wg = (xcd < r ? xcd * (q + 1) : r * (q + 1) + (xcd - r) * q) + idx;
        bm = wg / nbn; bn = wg - bm * nbn;
    } else {
        bm = blockIdx.x; bn = blockIdx.y;
    }

    const int wid = tid >> 6, lane = tid & 63;
    const int wm = wid >> 1, wn = wid & 1;
    const int frow = lane & 15, quad = lane >> 4;

    // ---- staging setup (hoisted out of K-loop) ----
    const int srow = tid >> 2, schunk = tid & 3;
    const int ssw = schunk ^ ((srow ^ (srow >> 2)) & 3);   // pre-swizzled chunk

    const u16* gA[PA]; int stA[PA];
#pragma unroll
    for (int p = 0; p < PA; p++) {
        int gm = bm * BM + srow + p * 64;
        int src = (gm < M) ? gm : -1;
        gA[p]  = (src >= 0) ? A + (size_t)src * K + ssw * 8 : zrow + ssw * 8;
        stA[p] = (src >= 0) ? 32 : 0;
    }
    const u16* gB[2];
#pragma unroll
    for (int p = 0; p < 2; p++)
        gB[p] = BT + (size_t)(bn * 128 + srow + p * 64) * K + ssw * 8;

    // ---- fragment-read offsets (constant per thread, swizzled chunk) ----
    const int csw = quad ^ ((frow ^ (frow >> 2)) & 3);
    int offA[MI], offB[4];
#pragma unroll
    for (int mi = 0; mi < MI; mi++)
        offA[mi] = (wm * (BM / 2) + mi * 16 + frow) * 32 + csw * 8;
#pragma unroll
    for (int ni = 0; ni < 4; ni++)
        offB[ni] = (wn * 64 + ni * 16 + frow) * 32 + csw * 8;

    f32x4 acc[MI][4] = {};

    auto stageAdv = [&](int buf) {
#pragma unroll
        for (int p = 0; p < PA; p++) {
            gload16(gA[p], &As[buf][tid * 8 + p * 2048]);
            gA[p] += stA[p];
        }
#pragma unroll
        for (int p = 0; p < 2; p++) {
            gload16(gB[p], &Bs[buf][tid * 8 + p * 2048]);
            gB[p] += 32;
        }
    };
    // loads per stage = PA + 2 (4 for BM=128, 3 for BM=64)
    auto wait_loads = [&]() {
        if constexpr (PA == 2) asm volatile("s_waitcnt vmcnt(4)" ::: "memory");
        else                   asm volatile("s_waitcnt vmcnt(3)" ::: "memory");
    };

    // prologue: tiles 0,1 in flight; drain tile0 only (counted); barrier
    stageAdv(0);
    stageAdv(1);
    wait_loads();
    __builtin_amdgcn_s_barrier();

    int cur = 0;
    const int NK = K / 32;
    for (int kt = 0; kt < NK; kt++) {
        bf16x8 af[MI], bfr[4];
#pragma unroll
        for (int mi = 0; mi < MI; mi++)
            af[mi] = *(const bf16x8*)&As[cur][offA[mi]];
#pragma unroll
        for (int ni = 0; ni < 4; ni++)
            bfr[ni] = *(const bf16x8*)&Bs[cur][offB[ni]];
        asm volatile("s_waitcnt lgkmcnt(0)" ::: "memory");  // our frag reads landed
        __builtin_amdgcn_s_barrier();                       // all readers done
        if (kt + 2 < NK) stageAdv(cur);                     // tile kt+2 -> buf[cur]

#pragma unroll
        for (int mi = 0; mi < MI; mi++)
#pragma unroll
            for (int ni = 0; ni < 4; ni++)
                acc[mi][ni] = __builtin_amdgcn_mfma_f32_16x16x32_bf16(
                    af[mi], bfr[ni], acc[mi][ni], 0, 0, 0);

        if (kt + 1 < NK) {
            // drain tile kt+1's loads (issued a full iteration ago)
            if (kt + 2 < NK) wait_loads();
            else asm volatile("s_waitcnt vmcnt(0)" ::: "memory");
            __builtin_amdgcn_s_barrier();
        }
        cur ^= 1;
    }

    // ---------------- epilogues ----------------
    if (EPI == EPI_MEGA && bn < 14) {
        // BM=128: block = 2 image rows (64px). wm=0 holds gh=2*oy,
        // wm=1 holds gh=2*oy+1; gw pairs live in acc i-pairs.
        __syncthreads();                       // all frag reads done; reuse As
        float* Pool = (float*)As;              // 32 x 128 fp32 = 16KB
        if (wm == 1) {
#pragma unroll
            for (int mi = 0; mi < MI; mi++)
#pragma unroll
            for (int ni = 0; ni < 4; ni++) {
                int ox0 = mi * 8 + quad * 2;
                int gnl = wn * 64 + ni * 16 + frow;
                Pool[(ox0 + 0) * 128 + gnl] = fmaxf(acc[mi][ni][0], acc[mi][ni][1]);
                Pool[(ox0 + 1) * 128 + gnl] = fmaxf(acc[mi][ni][2], acc[mi][ni][3]);
            }
        }
        __syncthreads();
        if (wm == 0) {
            int b = bm >> 5, oy = bm & 31;
            int wh = oy / 7, qy = oy - 7 * wh;   // q-third only
#pragma unroll
            for (int mi = 0; mi < MI; mi++)
#pragma unroll
            for (int ni = 0; ni < 4; ni++) {
                int ox0 = mi * 8 + quad * 2;
                int gnl = wn * 64 + ni * 16 + frow;
                int gn = bn * 128 + gnl;
                float bv = bias[gn];
                float v0 = fmaxf(fmaxf(acc[mi][ni][0], acc[mi][ni][1]),
                                 Pool[(ox0 + 0) * 128 + gnl]) + bv;
                float v1 = fmaxf(fmaxf(acc[mi][ni][2], acc[mi][ni][3]),
                                 Pool[(ox0 + 1) * 128 + gnl]) + bv;
                if (bn < 7) {
                    // skip third: pooled shortcut -> Yf (fp32)
                    size_t pix = (size_t)((b * 32 + oy) * 32 + ox0);
                    Yf[pix * 896 + gn] = v0;
                    Yf[(pix + 1) * 896 + gn] = v1;
                } else {
                    // q third: pooled q -> qp (bf16), window order
                    int col = gn - 896;
                    int ox1 = ox0 + 1;
                    int ww0 = ox0 / 7, qx0 = ox0 - 7 * ww0;
                    int ww1 = ox1 / 7, qx1 = ox1 - 7 * ww1;
                    int w0 = b * 25 + wh * 5 + ww0;
                    int w1 = b * 25 + wh * 5 + ww1;
                    Cb3[(size_t)(w0 * 49 + qy * 7 + qx0) * 896 + col] = f2bf(v0);
                    Cb3[(size_t)(w1 * 49 + qy * 7 + qx1) * 896 + col] = f2bf(v1);
                }
            }
        }
        return;
    }

    // element-wise epilogues: D lane layout col = lane&15, row = quad*4 + i
#pragma unroll
    for (int mi = 0; mi < MI; mi++)
#pragma unroll
    for (int ni = 0; ni < 4; ni++)
#pragma unroll
    for (int i = 0; i < 4; i++) {
        int gm = bm * BM + wm * (BM / 2) + mi * 16 + quad * 4 + i;
        int gn = bn * 128 + wn * 64 + ni * 16 + frow;
        if (gm >= M) continue;
        float val = acc[mi][ni][i] + bias[gn];
        if (EPI == EPI_MEGA) {
            int third = gn / 896;            // 2 => k, 3 => v (bn>=14 here)
            int col = gn - third * 896;
            u16* dst = (third == 2) ? Cb : Cb2;
            __builtin_nontemporal_store(f2bf(val), &dst[(size_t)gm * 896 + col]);
        } else if (EPI == EPI_GELU) {
            float ge = 0.5f * val * (1.0f + erff(val * 0.70710678118654752f));
            __builtin_nontemporal_store(f2bf(ge), &Cb[(size_t)gm * N + gn]);
        } else if (EPI == EPI_PROJ) {
            Yf[(size_t)gm * 896 + gn] += val;   // pixel space: y = shortcut + xo
        } else { // EPI_OUT: final output FP32
            __builtin_nontemporal_store(val + Yf[(size_t)gm * 896 + gn],
                                        &Of[(size_t)gm * 896 + gn]);
        }
    }
}

// ---------------- MFMA attention: one block per (window, head) ---------------
// K/V staged from pixel-space k_img/v_img with on-the-fly window gather;
// padded window rows (gh>=64 || gw>=64) read the bf16 qkv bias vector.
// Output ao written in PIXEL space (valid q rows only; windows disjoint).
__global__ __launch_bounds__(256) void attn_mfma(const u16* __restrict__ qp,
    const u16* __restrict__ kimg, const u16* __restrict__ vimg,
    const u16* __restrict__ qkvbf, u16* __restrict__ ao)
{
    __shared__ __align__(16) u16 Ps[64][232];
    __shared__ __align__(16) u16 KV[208 * 72];

    const float SCALE = 0.13363062095621219f;   // 56^-0.5
    const int w = blockIdx.x >> 4, h = blockIdx.x & 15;
    const int tid = threadIdx.x;
    const int wid = tid >> 6, lane = tid & 63;
    const int n16 = lane & 15, quad = lane >> 4;

    const int b = w / 25, wh = (w / 5) % 5, ww = w % 5;
    const int ghb = wh * 14, gwb = ww * 14;

    for (int idx = tid; idx < 64 * 232 / 8; idx += 256)
        *(uint4*)&Ps[0][idx * 8] = make_uint4(0u, 0u, 0u, 0u);
    for (int idx = tid; idx < 208 * 9; idx += 256) {
        int n = idx / 9, kc = (idx % 9) * 8;
        uint4 val = make_uint4(0u, 0u, 0u, 0u);
        if (n < 196 && kc < 56) {
            int ty = n / 14, tx = n - 14 * ty;
            int gh = ghb + ty, gw = gwb + tx;
            const u16* src = (gh < 64 && gw < 64)
                ? kimg + (size_t)((b * 64 + gh) * 64 + gw) * 896 + h * 56 + kc
                : qkvbf + 896 + h * 56 + kc;
            val = *(const uint4*)src;
        }
        *(uint4*)&KV[n * 72 + kc] = val;
    }
    bf16x8 qf[2];
    {
        int m = 16 * wid + n16;
        int row = w * 49 + (m < 49 ? m : 48);
        const u16* src = qp + (size_t)row * 896 + h * 56;
#pragma unroll
        for (int ks = 0; ks < 2; ks++) {
            int kk = ks * 32 + quad * 8;
            uint4 v = make_uint4(0u, 0u, 0u, 0u);
            if (kk < 56) v = *(const uint4*)(src + kk);
            qf[ks] = __builtin_bit_cast(bf16x8, v);
        }
    }
    __syncthreads();

    f32x4 S[13] = {};
#pragma unroll
    for (int nt = 0; nt < 13; nt++) {
#pragma unroll
        for (int ks = 0; ks < 2; ks++) {
            bf16x8 bf = *(const bf16x8*)&KV[(nt * 16 + n16) * 72 + ks * 32 + quad * 8];
            S[nt] = __builtin_amdgcn_mfma_f32_16x16x32_bf16(qf[ks], bf, S[nt], 0, 0, 0);
        }
    }
#pragma unroll
    for (int i = 0; i < 4; i++) {
        float mx = -3.0e38f;
#pragma unroll
        for (int nt = 0; nt < 13; nt++) {
            float v = S[nt][i] * SCALE;
            S[nt][i] = v;
            if (nt < 12 || n16 < 4) mx = fmaxf(mx, v);
        }
        mx = fmaxf(mx, __shfl_xor(mx, 1, 64));
        mx = fmaxf(mx, __shfl_xor(mx, 2, 64));
        mx = fmaxf(mx, __shfl_xor(mx, 4, 64));
        mx = fmaxf(mx, __shfl_xor(mx, 8, 64));
        float sm = 0.f;
#pragma unroll
        for (int nt = 0; nt < 13; nt++) {
            float e = (nt < 12 || n16 < 4) ? __expf(S[nt][i] - mx) : 0.f;
            S[nt][i] = e;
            sm += e;
        }
        sm += __shfl_xor(sm, 1, 64);
        sm += __shfl_xor(sm, 2, 64);
        sm += __shfl_xor(sm, 4, 64);
        sm += __shfl_xor(sm, 8, 64);
        float inv = 1.f / sm;
#pragma unroll
        for (int nt = 0; nt < 13; nt++) S[nt][i] *= inv;
    }
    __syncthreads();

#pragma unroll
    for (int nt = 0; nt < 13; nt++)
#pragma unroll
        for (int i = 0; i < 4; i++)
            Ps[16 * wid + 4 * quad + i][16 * nt + n16] = f2bf(S[nt][i]);

    // V-transpose staging: uint4 loads of pixel pairs, packed b32 LDS writes
    u16 (*Vs)[232] = reinterpret_cast<u16(*)[232]>(KV);
    for (int idx = tid; idx < 98 * 7; idx += 256) {
        int j2 = idx / 7, dc = idx % 7;
        int j = 2 * j2;
        int ty = j / 14, tx = j - 14 * ty;        // tx even <= 12
        int gh = ghb + ty, gw = gwb + tx;
        int off = h * 56 + dc * 8;
        const u16* p0 = (gh < 64 && gw < 64)
            ? vimg + (size_t)((b * 64 + gh) * 64 + gw) * 896 + off
            : qkvbf + 1792 + off;
        const u16* p1 = (gh < 64 && gw + 1 < 64)
            ? vimg + (size_t)((b * 64 + gh) * 64 + gw + 1) * 896 + off
            : qkvbf + 1792 + off;
        uint4 a = *(const uint4*)p0;
        uint4 bb = *(const uint4*)p1;
        u16 ua[8], ub[8];
        *(uint4*)ua = a; *(uint4*)ub = bb;
#pragma unroll
        for (int i = 0; i < 8; i++) {
            unsigned pair = (unsigned)ua[i] | ((unsigned)ub[i] << 16);
            *(unsigned*)&Vs[dc * 8 + i][j] = pair;
        }
    }
    for (int idx = tid; idx < 64 * 14; idx += 256) {
        int d = idx / 14, c = idx % 14;
        *(unsigned*)&Vs[d][196 + 2 * c] = 0u;
    }
    __syncthreads();

    f32x4 O[4] = {};
#pragma unroll
    for (int ks = 0; ks < 7; ks++) {
        bf16x8 a = *(const bf16x8*)&Ps[16 * wid + n16][ks * 32 + quad * 8];
#pragma unroll
        for (int nt = 0; nt < 4; nt++) {
            bf16x8 b2 = *(const bf16x8*)&Vs[16 * nt + n16][ks * 32 + quad * 8];
            O[nt] = __builtin_amdgcn_mfma_f32_16x16x32_bf16(a, b2, O[nt], 0, 0, 0);
        }
    }
#pragma unroll
    for (int nt = 0; nt < 4; nt++)
#pragma unroll
        for (int i = 0; i < 4; i++) {
            int m = 16 * wid + 4 * quad + i;
            int d = 16 * nt + n16;
            if (m < 49 && d < 56) {
                int qy = m / 7, qx = m - 7 * qy;
                int oy = wh * 7 + qy, ox = ww * 7 + qx;
                if (oy < 32 && ox < 32) {
                    size_t pix = (size_t)((b * 32 + oy) * 32 + ox);
                    ao[pix * 896 + h * 56 + d] = f2bf(O[nt][i]);
                }
            }
        }
}

extern "C" void kernel_launch(void* const* d_in, const int* in_sizes, int n_in,
                              void* d_out, int out_size, void* d_ws, size_t ws_size,
                              hipStream_t stream)
{
    const float* x    = (const float*)d_in[0];
    const float* ln1g = (const float*)d_in[1];
    const float* ln1b = (const float*)d_in[2];
    const float* qkvw = (const float*)d_in[3];
    const float* qkvb = (const float*)d_in[4];
    const float* pw   = (const float*)d_in[5];
    const float* pb   = (const float*)d_in[6];
    const float* sw   = (const float*)d_in[7];
    const float* sb   = (const float*)d_in[8];
    const float* ln2g = (const float*)d_in[9];
    const float* ln2b = (const float*)d_in[10];
    const float* m1w  = (const float*)d_in[11];
    const float* m1b  = (const float*)d_in[12];
    const float* m2w  = (const float*)d_in[13];
    const float* m2b  = (const float*)d_in[14];

    char* ws = (char*)d_ws;
    // ws layout, lifetime-aliased. Peak ~216.1 MB.
    u16*   kimg = (u16*)(ws + 0);             // 58,720,256 B; after attn: m1
    u16*   vimg = (u16*)(ws + 58720256);      // 58,720,256 B; after attn: m1wT/m2wT
    u16*   hn   = (u16*)(ws + 117440512);     // 29,360,128 B; later hn2
    float* Yf   = (float*)(ws + 146800640);   // 29,360,128 B (8192*896 fp32)
    u16*   qp   = (u16*)(ws + 176160768);     // 17,561,600 B
    u16*   ao   = (u16*)(ws + 193722368);     // 14,680,064 B (8192x896 pixel)
    u16*   bigT = (u16*)(ws + 211283968);     //  3,211,264 B ([sw|qkv]^T 3584x448)
    u16*   pwT  = (u16*)(ws + 214495232);     //  1,605,632 B (896x896)
    u16*   qkvbf= (u16*)(ws + 216100864);     //      5,376 B (2688 bf16)
    float* cbias= (float*)(ws + 216106240);   //     14,336 B (3584 fp32)
    u16*   zrow = (u16*)(ws + 216120576);     //        256 B zeros
    u16*   m1   = kimg;                       // 58,720,256 B (8192x3584)
    u16*   hn2  = hn;
    u16*   m1wT = vimg;                       // 6,422,528 B (3584x896)
    u16*   m2wT = (u16*)(ws + 58720256 + 6422528); // 6,422,528 B (896x3584)
    float* outf = (float*)d_out;

    // 0. prep: zeros, biases, weight transposes, qp boundary fill
    zfill<<<1, 128, 0, stream>>>(zrow);
    cvt_bias<<<11, 256, 0, stream>>>(qkvb, qkvbf, 2688);
    concat_bias<<<14, 256, 0, stream>>>(sb, qkvb, cbias);
    qfill<<<4288, 256, 0, stream>>>(qkvb, qp);
    transpose_w<<<dim3(14, 14), 256, 0, stream>>>(sw,   bigT, 448, 896);
    transpose_w<<<dim3(14, 42), 256, 0, stream>>>(qkvw, bigT + (size_t)896 * 448,
                                                  448, 2688);
    transpose_w<<<dim3(28, 14), 256, 0, stream>>>(pw, pwT, 896, 896);
    // 1. hn = LN1(x)
    ln_kernel<448><<<8192, 256, 0, stream>>>(x, ln1g, ln1b, hn, 32768);
    // 2-7. MEGA: [shortcut-pool | q-pool | k | v] = hn @ [sw|Wqkv] + [sb|bqkv]
    gemm_t<128, EPI_MEGA, 1><<<256 * 28, 256, 0, stream>>>(
        hn, bigT, zrow, cbias, kimg, vimg, qp, Yf, nullptr,
        32768, 3584, 448, 28);
    // 8. attention (MFMA; pixel-space ao output)
    attn_mfma<<<3200, 256, 0, stream>>>(qp, kimg, vimg, qkvbf, ao);
    // 8b. transpose mlp weights into dead vimg region
    transpose_w<<<dim3(28, 56),  256, 0, stream>>>(m1w, m1wT, 896, 3584);
    transpose_w<<<dim3(112, 14), 256, 0, stream>>>(m2w, m2wT, 3584, 896);
    // 9. y += ao @ proj_w + proj_b   (pixel space, M=8192)
    gemm_t<64, EPI_PROJ, 1><<<128 * 7, 256, 0, stream>>>(
        ao, pwT, zrow, pb, nullptr, nullptr, nullptr, Yf, nullptr,
        8192, 896, 896, 7);
    // 10. hn2 = LN2(y)
    ln_kernel<896><<<2048, 256, 0, stream>>>(Yf, ln2g, ln2b, hn2, 8192);
    // 11. m1 = gelu(hn2 @ mlp1_w + mlp1_b)   (natural order: B large)
    gemm_t<128, EPI_GELU, 0><<<dim3(64, 28), 256, 0, stream>>>(
        hn2, m1wT, zrow, m1b, m1, nullptr, nullptr, nullptr, nullptr,
        8192, 3584, 896, 28);
    // 12. out = y + m1 @ mlp2_w + mlp2_b   (fp32 nontemporal store)
    gemm_t<64, EPI_OUT, 0><<<dim3(128, 7), 256, 0, stream>>>(
        m1, m2wT, zrow, m2b, nullptr, nullptr, nullptr, Yf, outf,
        8192, 896, 3584, 7);
}

// Round 13
// 611.307 us; speedup vs baseline: 1.0767x; 1.0767x over previous
//
#include <hip/hip_runtime.h>
#include <hip/hip_bf16.h>

typedef unsigned short u16;
typedef __bf16 bf16x8 __attribute__((ext_vector_type(8)));
typedef float f32x4 __attribute__((ext_vector_type(4)));

__device__ __forceinline__ float bf2f(u16 u) {
    unsigned v = ((unsigned)u) << 16;
    return __builtin_bit_cast(float, v);
}
__device__ __forceinline__ u16 f2bf(float f) {
    unsigned x = __builtin_bit_cast(unsigned, f);
    unsigned r = x + (0x7fffu + ((x >> 16) & 1u));   // RNE
    return (u16)(r >> 16);
}
__device__ __forceinline__ void gload16(const void* g, void* l) {
    __builtin_amdgcn_global_load_lds(
        (const __attribute__((address_space(1))) void*)g,
        (__attribute__((address_space(3))) void*)l, 16, 0, 0);
}

// ---------------- weight transpose+convert: fp32 [K][N] -> bf16 [N][K] -------
__global__ __launch_bounds__(256) void transpose_w(const float* __restrict__ src,
    u16* __restrict__ dst, int K, int N)
{
    __shared__ u16 T[64][33];
    int k0 = blockIdx.x * 32, n0 = blockIdx.y * 64;
    int t = threadIdx.x;
    int nc = t & 63, krb = (t >> 6) * 8;
#pragma unroll
    for (int j = 0; j < 8; j++) {
        int kr = krb + j;
        T[nc][kr] = f2bf(src[(size_t)(k0 + kr) * N + n0 + nc]);
    }
    __syncthreads();
    int r = t >> 2, c0 = (t & 3) * 8;
    u16 tmp[8];
#pragma unroll
    for (int i = 0; i < 8; i++) tmp[i] = T[r][c0 + i];
    *(uint4*)&dst[(size_t)(n0 + r) * K + k0 + c0] = *(uint4*)tmp;
}

__global__ void zfill(u16* p) { p[threadIdx.x] = 0; }

__global__ __launch_bounds__(256) void cvt_bias(const float* __restrict__ s,
                                                u16* __restrict__ d, int n)
{
    int i = blockIdx.x * 256 + threadIdx.x;
    if (i < n) d[i] = f2bf(s[i]);
}

// ---- combined bias [sb | qkvb] (3584 fp32) ---------------------------------
__global__ __launch_bounds__(256) void concat_bias(const float* __restrict__ sb,
    const float* __restrict__ qkvb, float* __restrict__ cb)
{
    int i = blockIdx.x * 256 + threadIdx.x;
    if (i < 896) cb[i] = sb[i];
    else if (i < 3584) cb[i] = qkvb[i - 896];
}

// ---- qp boundary fill: entries whose 4 pool taps are all padded -> bq ------
__global__ __launch_bounds__(256) void qfill(const float* __restrict__ qkvb,
                                             u16* __restrict__ qp)
{
    int id = blockIdx.x * 256 + threadIdx.x;
    if (id >= 9800 * 112) return;
    int c8 = id % 112, rq = id / 112;
    int q = rq % 49, w = rq / 49;
    int qy = q / 7, qx = q - 7 * qy;
    int wh = (w / 5) % 5, ww = w % 5;
    if (!((wh == 4 && qy >= 4) || (ww == 4 && qx >= 4))) return;
    int c = c8 * 8;
    u16 o[8];
#pragma unroll
    for (int i = 0; i < 8; i++) o[i] = f2bf(qkvb[c + i]);
    *(uint4*)&qp[(size_t)rq * 896 + c] = *(uint4*)o;
}

// ---------------- LayerNorm: one wave per pixel (fp32 in, bf16 out) ----------
template<int C>
__global__ __launch_bounds__(256) void ln_kernel(const float* __restrict__ xf,
    const float* __restrict__ g, const float* __restrict__ b,
    u16* __restrict__ out, int npix)
{
    int wid = threadIdx.x >> 6, lane = threadIdx.x & 63;
    int pix = blockIdx.x * 4 + wid;
    if (pix >= npix) return;
    constexpr int J = C / 64;
    float v[J];
    float s = 0.f, s2 = 0.f;
#pragma unroll
    for (int j = 0; j < J; j++) {
        int c = lane + j * 64;
        float t = xf[(size_t)pix * C + c];
        v[j] = t; s += t; s2 += t * t;
    }
#pragma unroll
    for (int off = 32; off; off >>= 1) {
        s  += __shfl_xor(s,  off, 64);
        s2 += __shfl_xor(s2, off, 64);
    }
    float mean = s / C;
    float var = fmaxf(s2 / C - mean * mean, 0.f);
    float rs = rsqrtf(var + 1e-6f);
#pragma unroll
    for (int j = 0; j < J; j++) {
        int c = lane + j * 64;
        float o = (v[j] - mean) * rs * g[c] + b[c];
        out[(size_t)pix * C + c] = f2bf(o);
    }
}

// ---------------- BMx128 MFMA GEMM, BK=32, 2-buffer counted-vmcnt ------------
// Converged config (R4): BM=128 3-4 blk/CU; BM=256/8-phase/3-buffer all
// regressed — cross-block overlap hides the lockstep-phase latency. Mega rate
// (598 TF) is ~98.5% of the 2-phase structural ceiling (m233: 607 TF).
// NOTE (R12 lesson): nontemporal stores on scalar u16/f32 element stores
// REGRESS (WRITE 194->214 MB, dur +8 us) — they defeat L2 write-combining.
// Plain stores; the extra L2 fetch traffic rides free under the issue-bound
// loop.
// EPI_MEGA (N=3584 = [skip|q|k|v]): bn<7 skip w/ fused 2x2 pool -> Yf fp32;
// bn 7-13 q w/ fused pool -> qp bf16 (every pixel pair is a valid window pool
// pair since WIN=14 even); bn 14-20 k -> kimg; bn 21-27 v -> vimg.
// EPI_PROJ (pixel space): Yf[gm] += val, M=8192 (ao written pixel-space by
// attn — windows disjoint, 16% padding FLOPs eliminated).
enum { EPI_GELU = 1, EPI_PROJ = 2, EPI_OUT = 3, EPI_MEGA = 6 };

template<int BM, int EPI, int SWZ>
__global__ __launch_bounds__(256, (BM == 64) ? 6 : 4) void gemm_t(
    const u16* __restrict__ A, const u16* __restrict__ BT,
    const u16* __restrict__ zrow, const float* __restrict__ bias,
    u16* __restrict__ Cb, u16* __restrict__ Cb2, u16* __restrict__ Cb3,
    float* __restrict__ Yf, float* __restrict__ Of,
    int M, int N, int K, int nbn)
{
    constexpr int MI = BM / 32;    // per-wave 16-row frags (wave covers BM/2)
    constexpr int PA = BM / 64;    // A staging units (256 thr x 16B = 4KB each)
    constexpr int ASZ = BM * 32, BSZ = 128 * 32;
    __shared__ __align__(16) u16 As[2][ASZ];
    __shared__ __align__(16) u16 Bs[2][BSZ];

    const int tid = threadIdx.x;
    int bm, bn;
    if (SWZ) {
        int nwg = gridDim.x, orig = blockIdx.x;
        int q = nwg >> 3, r = nwg & 7;
        int xcd = orig & 7, idx = orig >> 3;
        int wg = (xcd < r ? xcd * (q + 1) : r * (q + 1) + (xcd - r) * q) + idx;
        bm = wg / nbn; bn = wg - bm * nbn;
    } else {
        bm = blockIdx.x; bn = blockIdx.y;
    }

    const int wid = tid >> 6, lane = tid & 63;
    const int wm = wid >> 1, wn = wid & 1;
    const int frow = lane & 15, quad = lane >> 4;

    // ---- staging setup (hoisted out of K-loop) ----
    const int srow = tid >> 2, schunk = tid & 3;
    const int ssw = schunk ^ ((srow ^ (srow >> 2)) & 3);   // pre-swizzled chunk

    const u16* gA[PA]; int stA[PA];
#pragma unroll
    for (int p = 0; p < PA; p++) {
        int gm = bm * BM + srow + p * 64;
        int src = (gm < M) ? gm : -1;
        gA[p]  = (src >= 0) ? A + (size_t)src * K + ssw * 8 : zrow + ssw * 8;
        stA[p] = (src >= 0) ? 32 : 0;
    }
    const u16* gB[2];
#pragma unroll
    for (int p = 0; p < 2; p++)
        gB[p] = BT + (size_t)(bn * 128 + srow + p * 64) * K + ssw * 8;

    // ---- fragment-read offsets (constant per thread, swizzled chunk) ----
    const int csw = quad ^ ((frow ^ (frow >> 2)) & 3);
    int offA[MI], offB[4];
#pragma unroll
    for (int mi = 0; mi < MI; mi++)
        offA[mi] = (wm * (BM / 2) + mi * 16 + frow) * 32 + csw * 8;
#pragma unroll
    for (int ni = 0; ni < 4; ni++)
        offB[ni] = (wn * 64 + ni * 16 + frow) * 32 + csw * 8;

    f32x4 acc[MI][4] = {};

    auto stageAdv = [&](int buf) {
#pragma unroll
        for (int p = 0; p < PA; p++) {
            gload16(gA[p], &As[buf][tid * 8 + p * 2048]);
            gA[p] += stA[p];
        }
#pragma unroll
        for (int p = 0; p < 2; p++) {
            gload16(gB[p], &Bs[buf][tid * 8 + p * 2048]);
            gB[p] += 32;
        }
    };
    // loads per stage = PA + 2 (4 for BM=128, 3 for BM=64)
    auto wait_loads = [&]() {
        if constexpr (PA == 2) asm volatile("s_waitcnt vmcnt(4)" ::: "memory");
        else                   asm volatile("s_waitcnt vmcnt(3)" ::: "memory");
    };

    // prologue: tiles 0,1 in flight; drain tile0 only (counted); barrier
    stageAdv(0);
    stageAdv(1);
    wait_loads();
    __builtin_amdgcn_s_barrier();

    int cur = 0;
    const int NK = K / 32;
    for (int kt = 0; kt < NK; kt++) {
        bf16x8 af[MI], bfr[4];
#pragma unroll
        for (int mi = 0; mi < MI; mi++)
            af[mi] = *(const bf16x8*)&As[cur][offA[mi]];
#pragma unroll
        for (int ni = 0; ni < 4; ni++)
            bfr[ni] = *(const bf16x8*)&Bs[cur][offB[ni]];
        asm volatile("s_waitcnt lgkmcnt(0)" ::: "memory");  // our frag reads landed
        __builtin_amdgcn_s_barrier();                       // all readers done
        if (kt + 2 < NK) stageAdv(cur);                     // tile kt+2 -> buf[cur]

#pragma unroll
        for (int mi = 0; mi < MI; mi++)
#pragma unroll
            for (int ni = 0; ni < 4; ni++)
                acc[mi][ni] = __builtin_amdgcn_mfma_f32_16x16x32_bf16(
                    af[mi], bfr[ni], acc[mi][ni], 0, 0, 0);

        if (kt + 1 < NK) {
            // drain tile kt+1's loads (issued a full iteration ago)
            if (kt + 2 < NK) wait_loads();
            else asm volatile("s_waitcnt vmcnt(0)" ::: "memory");
            __builtin_amdgcn_s_barrier();
        }
        cur ^= 1;
    }

    // ---------------- epilogues ----------------
    if (EPI == EPI_MEGA && bn < 14) {
        // BM=128: block = 2 image rows (64px). wm=0 holds gh=2*oy,
        // wm=1 holds gh=2*oy+1; gw pairs live in acc i-pairs.
        __syncthreads();                       // all frag reads done; reuse As
        float* Pool = (float*)As;              // 32 x 128 fp32 = 16KB
        if (wm == 1) {
#pragma unroll
            for (int mi = 0; mi < MI; mi++)
#pragma unroll
            for (int ni = 0; ni < 4; ni++) {
                int ox0 = mi * 8 + quad * 2;
                int gnl = wn * 64 + ni * 16 + frow;
                Pool[(ox0 + 0) * 128 + gnl] = fmaxf(acc[mi][ni][0], acc[mi][ni][1]);
                Pool[(ox0 + 1) * 128 + gnl] = fmaxf(acc[mi][ni][2], acc[mi][ni][3]);
            }
        }
        __syncthreads();
        if (wm == 0) {
            int b = bm >> 5, oy = bm & 31;
            int wh = oy / 7, qy = oy - 7 * wh;   // q-third only
#pragma unroll
            for (int mi = 0; mi < MI; mi++)
#pragma unroll
            for (int ni = 0; ni < 4; ni++) {
                int ox0 = mi * 8 + quad * 2;
                int gnl = wn * 64 + ni * 16 + frow;
                int gn = bn * 128 + gnl;
                float bv = bias[gn];
                float v0 = fmaxf(fmaxf(acc[mi][ni][0], acc[mi][ni][1]),
                                 Pool[(ox0 + 0) * 128 + gnl]) + bv;
                float v1 = fmaxf(fmaxf(acc[mi][ni][2], acc[mi][ni][3]),
                                 Pool[(ox0 + 1) * 128 + gnl]) + bv;
                if (bn < 7) {
                    // skip third: pooled shortcut -> Yf (fp32)
                    size_t pix = (size_t)((b * 32 + oy) * 32 + ox0);
                    Yf[pix * 896 + gn] = v0;
                    Yf[(pix + 1) * 896 + gn] = v1;
                } else {
                    // q third: pooled q -> qp (bf16), window order
                    int col = gn - 896;
                    int ox1 = ox0 + 1;
                    int ww0 = ox0 / 7, qx0 = ox0 - 7 * ww0;
                    int ww1 = ox1 / 7, qx1 = ox1 - 7 * ww1;
                    int w0 = b * 25 + wh * 5 + ww0;
                    int w1 = b * 25 + wh * 5 + ww1;
                    Cb3[(size_t)(w0 * 49 + qy * 7 + qx0) * 896 + col] = f2bf(v0);
                    Cb3[(size_t)(w1 * 49 + qy * 7 + qx1) * 896 + col] = f2bf(v1);
                }
            }
        }
        return;
    }

    // element-wise epilogues: D lane layout col = lane&15, row = quad*4 + i
#pragma unroll
    for (int mi = 0; mi < MI; mi++)
#pragma unroll
    for (int ni = 0; ni < 4; ni++)
#pragma unroll
    for (int i = 0; i < 4; i++) {
        int gm = bm * BM + wm * (BM / 2) + mi * 16 + quad * 4 + i;
        int gn = bn * 128 + wn * 64 + ni * 16 + frow;
        if (gm >= M) continue;
        float val = acc[mi][ni][i] + bias[gn];
        if (EPI == EPI_MEGA) {
            int third = gn / 896;            // 2 => k, 3 => v (bn>=14 here)
            int col = gn - third * 896;
            u16* dst = (third == 2) ? Cb : Cb2;
            dst[(size_t)gm * 896 + col] = f2bf(val);
        } else if (EPI == EPI_GELU) {
            float ge = 0.5f * val * (1.0f + erff(val * 0.70710678118654752f));
            Cb[(size_t)gm * N + gn] = f2bf(ge);
        } else if (EPI == EPI_PROJ) {
            Yf[(size_t)gm * 896 + gn] += val;   // pixel space: y = shortcut + xo
        } else { // EPI_OUT: final output FP32
            Of[(size_t)gm * 896 + gn] = val + Yf[(size_t)gm * 896 + gn];
        }
    }
}

// ---------------- MFMA attention: one block per (window, head) ---------------
// K/V staged from pixel-space k_img/v_img with on-the-fly window gather;
// padded window rows (gh>=64 || gw>=64) read the bf16 qkv bias vector.
// Output ao written in PIXEL space (valid q rows only; windows disjoint).
__global__ __launch_bounds__(256) void attn_mfma(const u16* __restrict__ qp,
    const u16* __restrict__ kimg, const u16* __restrict__ vimg,
    const u16* __restrict__ qkvbf, u16* __restrict__ ao)
{
    __shared__ __align__(16) u16 Ps[64][232];
    __shared__ __align__(16) u16 KV[208 * 72];

    const float SCALE = 0.13363062095621219f;   // 56^-0.5
    const int w = blockIdx.x >> 4, h = blockIdx.x & 15;
    const int tid = threadIdx.x;
    const int wid = tid >> 6, lane = tid & 63;
    const int n16 = lane & 15, quad = lane >> 4;

    const int b = w / 25, wh = (w / 5) % 5, ww = w % 5;
    const int ghb = wh * 14, gwb = ww * 14;

    for (int idx = tid; idx < 64 * 232 / 8; idx += 256)
        *(uint4*)&Ps[0][idx * 8] = make_uint4(0u, 0u, 0u, 0u);
    for (int idx = tid; idx < 208 * 9; idx += 256) {
        int n = idx / 9, kc = (idx % 9) * 8;
        uint4 val = make_uint4(0u, 0u, 0u, 0u);
        if (n < 196 && kc < 56) {
            int ty = n / 14, tx = n - 14 * ty;
            int gh = ghb + ty, gw = gwb + tx;
            const u16* src = (gh < 64 && gw < 64)
                ? kimg + (size_t)((b * 64 + gh) * 64 + gw) * 896 + h * 56 + kc
                : qkvbf + 896 + h * 56 + kc;
            val = *(const uint4*)src;
        }
        *(uint4*)&KV[n * 72 + kc] = val;
    }
    bf16x8 qf[2];
    {
        int m = 16 * wid + n16;
        int row = w * 49 + (m < 49 ? m : 48);
        const u16* src = qp + (size_t)row * 896 + h * 56;
#pragma unroll
        for (int ks = 0; ks < 2; ks++) {
            int kk = ks * 32 + quad * 8;
            uint4 v = make_uint4(0u, 0u, 0u, 0u);
            if (kk < 56) v = *(const uint4*)(src + kk);
            qf[ks] = __builtin_bit_cast(bf16x8, v);
        }
    }
    __syncthreads();

    f32x4 S[13] = {};
#pragma unroll
    for (int nt = 0; nt < 13; nt++) {
#pragma unroll
        for (int ks = 0; ks < 2; ks++) {
            bf16x8 bf = *(const bf16x8*)&KV[(nt * 16 + n16) * 72 + ks * 32 + quad * 8];
            S[nt] = __builtin_amdgcn_mfma_f32_16x16x32_bf16(qf[ks], bf, S[nt], 0, 0, 0);
        }
    }
#pragma unroll
    for (int i = 0; i < 4; i++) {
        float mx = -3.0e38f;
#pragma unroll
        for (int nt = 0; nt < 13; nt++) {
            float v = S[nt][i] * SCALE;
            S[nt][i] = v;
            if (nt < 12 || n16 < 4) mx = fmaxf(mx, v);
        }
        mx = fmaxf(mx, __shfl_xor(mx, 1, 64));
        mx = fmaxf(mx, __shfl_xor(mx, 2, 64));
        mx = fmaxf(mx, __shfl_xor(mx, 4, 64));
        mx = fmaxf(mx, __shfl_xor(mx, 8, 64));
        float sm = 0.f;
#pragma unroll
        for (int nt = 0; nt < 13; nt++) {
            float e = (nt < 12 || n16 < 4) ? __expf(S[nt][i] - mx) : 0.f;
            S[nt][i] = e;
            sm += e;
        }
        sm += __shfl_xor(sm, 1, 64);
        sm += __shfl_xor(sm, 2, 64);
        sm += __shfl_xor(sm, 4, 64);
        sm += __shfl_xor(sm, 8, 64);
        float inv = 1.f / sm;
#pragma unroll
        for (int nt = 0; nt < 13; nt++) S[nt][i] *= inv;
    }
    __syncthreads();

#pragma unroll
    for (int nt = 0; nt < 13; nt++)
#pragma unroll
        for (int i = 0; i < 4; i++)
            Ps[16 * wid + 4 * quad + i][16 * nt + n16] = f2bf(S[nt][i]);

    // V-transpose staging: uint4 loads of pixel pairs, packed b32 LDS writes
    u16 (*Vs)[232] = reinterpret_cast<u16(*)[232]>(KV);
    for (int idx = tid; idx < 98 * 7; idx += 256) {
        int j2 = idx / 7, dc = idx % 7;
        int j = 2 * j2;
        int ty = j / 14, tx = j - 14 * ty;        // tx even <= 12
        int gh = ghb + ty, gw = gwb + tx;
        int off = h * 56 + dc * 8;
        const u16* p0 = (gh < 64 && gw < 64)
            ? vimg + (size_t)((b * 64 + gh) * 64 + gw) * 896 + off
            : qkvbf + 1792 + off;
        const u16* p1 = (gh < 64 && gw + 1 < 64)
            ? vimg + (size_t)((b * 64 + gh) * 64 + gw + 1) * 896 + off
            : qkvbf + 1792 + off;
        uint4 a = *(const uint4*)p0;
        uint4 bb = *(const uint4*)p1;
        u16 ua[8], ub[8];
        *(uint4*)ua = a; *(uint4*)ub = bb;
#pragma unroll
        for (int i = 0; i < 8; i++) {
            unsigned pair = (unsigned)ua[i] | ((unsigned)ub[i] << 16);
            *(unsigned*)&Vs[dc * 8 + i][j] = pair;
        }
    }
    for (int idx = tid; idx < 64 * 14; idx += 256) {
        int d = idx / 14, c = idx % 14;
        *(unsigned*)&Vs[d][196 + 2 * c] = 0u;
    }
    __syncthreads();

    f32x4 O[4] = {};
#pragma unroll
    for (int ks = 0; ks < 7; ks++) {
        bf16x8 a = *(const bf16x8*)&Ps[16 * wid + n16][ks * 32 + quad * 8];
#pragma unroll
        for (int nt = 0; nt < 4; nt++) {
            bf16x8 b2 = *(const bf16x8*)&Vs[16 * nt + n16][ks * 32 + quad * 8];
            O[nt] = __builtin_amdgcn_mfma_f32_16x16x32_bf16(a, b2, O[nt], 0, 0, 0);
        }
    }
#pragma unroll
    for (int nt = 0; nt < 4; nt++)
#pragma unroll
        for (int i = 0; i < 4; i++) {
            int m = 16 * wid + 4 * quad + i;
            int d = 16 * nt + n16;
            if (m < 49 && d < 56) {
                int qy = m / 7, qx = m - 7 * qy;
                int oy = wh * 7 + qy, ox = ww * 7 + qx;
                if (oy < 32 && ox < 32) {
                    size_t pix = (size_t)((b * 32 + oy) * 32 + ox);
                    ao[pix * 896 + h * 56 + d] = f2bf(O[nt][i]);
                }
            }
        }
}

extern "C" void kernel_launch(void* const* d_in, const int* in_sizes, int n_in,
                              void* d_out, int out_size, void* d_ws, size_t ws_size,
                              hipStream_t stream)
{
    const float* x    = (const float*)d_in[0];
    const float* ln1g = (const float*)d_in[1];
    const float* ln1b = (const float*)d_in[2];
    const float* qkvw = (const float*)d_in[3];
    const float* qkvb = (const float*)d_in[4];
    const float* pw   = (const float*)d_in[5];
    const float* pb   = (const float*)d_in[6];
    const float* sw   = (const float*)d_in[7];
    const float* sb   = (const float*)d_in[8];
    const float* ln2g = (const float*)d_in[9];
    const float* ln2b = (const float*)d_in[10];
    const float* m1w  = (const float*)d_in[11];
    const float* m1b  = (const float*)d_in[12];
    const float* m2w  = (const float*)d_in[13];
    const float* m2b  = (const float*)d_in[14];

    char* ws = (char*)d_ws;
    // ws layout, lifetime-aliased. Peak ~216.1 MB.
    u16*   kimg = (u16*)(ws + 0);             // 58,720,256 B; after attn: m1
    u16*   vimg = (u16*)(ws + 58720256);      // 58,720,256 B; after attn: m1wT/m2wT
    u16*   hn   = (u16*)(ws + 117440512);     // 29,360,128 B; later hn2
    float* Yf   = (float*)(ws + 146800640);   // 29,360,128 B (8192*896 fp32)
    u16*   qp   = (u16*)(ws + 176160768);     // 17,561,600 B
    u16*   ao   = (u16*)(ws + 193722368);     // 14,680,064 B (8192x896 pixel)
    u16*   bigT = (u16*)(ws + 211283968);     //  3,211,264 B ([sw|qkv]^T 3584x448)
    u16*   pwT  = (u16*)(ws + 214495232);     //  1,605,632 B (896x896)
    u16*   qkvbf= (u16*)(ws + 216100864);     //      5,376 B (2688 bf16)
    float* cbias= (float*)(ws + 216106240);   //     14,336 B (3584 fp32)
    u16*   zrow = (u16*)(ws + 216120576);     //        256 B zeros
    u16*   m1   = kimg;                       // 58,720,256 B (8192x3584)
    u16*   hn2  = hn;
    u16*   m1wT = vimg;                       // 6,422,528 B (3584x896)
    u16*   m2wT = (u16*)(ws + 58720256 + 6422528); // 6,422,528 B (896x3584)
    float* outf = (float*)d_out;

    // 0. prep: zeros, biases, weight transposes, qp boundary fill
    zfill<<<1, 128, 0, stream>>>(zrow);
    cvt_bias<<<11, 256, 0, stream>>>(qkvb, qkvbf, 2688);
    concat_bias<<<14, 256, 0, stream>>>(sb, qkvb, cbias);
    qfill<<<4288, 256, 0, stream>>>(qkvb, qp);
    transpose_w<<<dim3(14, 14), 256, 0, stream>>>(sw,   bigT, 448, 896);
    transpose_w<<<dim3(14, 42), 256, 0, stream>>>(qkvw, bigT + (size_t)896 * 448,
                                                  448, 2688);
    transpose_w<<<dim3(28, 14), 256, 0, stream>>>(pw, pwT, 896, 896);
    // 1. hn = LN1(x)
    ln_kernel<448><<<8192, 256, 0, stream>>>(x, ln1g, ln1b, hn, 32768);
    // 2-7. MEGA: [shortcut-pool | q-pool | k | v] = hn @ [sw|Wqkv] + [sb|bqkv]
    gemm_t<128, EPI_MEGA, 1><<<256 * 28, 256, 0, stream>>>(
        hn, bigT, zrow, cbias, kimg, vimg, qp, Yf, nullptr,
        32768, 3584, 448, 28);
    // 8. attention (MFMA; pixel-space ao output)
    attn_mfma<<<3200, 256, 0, stream>>>(qp, kimg, vimg, qkvbf, ao);
    // 8b. transpose mlp weights into dead vimg region
    transpose_w<<<dim3(28, 56),  256, 0, stream>>>(m1w, m1wT, 896, 3584);
    transpose_w<<<dim3(112, 14), 256, 0, stream>>>(m2w, m2wT, 3584, 896);
    // 9. y += ao @ proj_w + proj_b   (pixel space, M=8192)
    gemm_t<64, EPI_PROJ, 1><<<128 * 7, 256, 0, stream>>>(
        ao, pwT, zrow, pb, nullptr, nullptr, nullptr, Yf, nullptr,
        8192, 896, 896, 7);
    // 10. hn2 = LN2(y)
    ln_kernel<896><<<2048, 256, 0, stream>>>(Yf, ln2g, ln2b, hn2, 8192);
    // 11. m1 = gelu(hn2 @ mlp1_w + mlp1_b)   (natural order: B large)
    gemm_t<128, EPI_GELU, 0><<<dim3(64, 28), 256, 0, stream>>>(
        hn2, m1wT, zrow, m1b, m1, nullptr, nullptr, nullptr, nullptr,
        8192, 3584, 896, 28);
    // 12. out = y + m1 @ mlp2_w + mlp2_b   (fp32 store)
    gemm_t<64, EPI_OUT, 0><<<dim3(128, 7), 256, 0, stream>>>(
        m1, m2wT, zrow, m2b, nullptr, nullptr, nullptr, Yf, outf,
        8192, 896, 3584, 7);
}

// Round 14
// 605.307 us; speedup vs baseline: 1.0873x; 1.0099x over previous
//
#include <hip/hip_runtime.h>
#include <hip/hip_bf16.h>

typedef unsigned short u16;
typedef __bf16 bf16x8 __attribute__((ext_vector_type(8)));
typedef float f32x4 __attribute__((ext_vector_type(4)));

__device__ __forceinline__ float bf2f(u16 u) {
    unsigned v = ((unsigned)u) << 16;
    return __builtin_bit_cast(float, v);
}
__device__ __forceinline__ u16 f2bf(float f) {
    unsigned x = __builtin_bit_cast(unsigned, f);
    unsigned r = x + (0x7fffu + ((x >> 16) & 1u));   // RNE
    return (u16)(r >> 16);
}
__device__ __forceinline__ void gload16(const void* g, void* l) {
    __builtin_amdgcn_global_load_lds(
        (const __attribute__((address_space(1))) void*)g,
        (__attribute__((address_space(3))) void*)l, 16, 0, 0);
}

// ---------------- weight transpose tile: fp32 [K][N] -> bf16 [N][K] ----------
__device__ __forceinline__ void transpose_tile(const float* __restrict__ src,
    u16* __restrict__ dst, int K, int N, int bx, int by, int t)
{
    __shared__ u16 T[64][33];
    int k0 = bx * 32, n0 = by * 64;
    int nc = t & 63, krb = (t >> 6) * 8;
#pragma unroll
    for (int j = 0; j < 8; j++) {
        int kr = krb + j;
        T[nc][kr] = f2bf(src[(size_t)(k0 + kr) * N + n0 + nc]);
    }
    __syncthreads();
    int r = t >> 2, c0 = (t & 3) * 8;
    u16 tmp[8];
#pragma unroll
    for (int i = 0; i < 8; i++) tmp[i] = T[r][c0 + i];
    *(uint4*)&dst[(size_t)(n0 + r) * K + k0 + c0] = *(uint4*)tmp;
}

// sw (196 blks) | qkvw (588) | pw (392) in one launch
__global__ __launch_bounds__(256) void transpose3(const float* __restrict__ sw,
    const float* __restrict__ qkvw, const float* __restrict__ pw,
    u16* __restrict__ bigT, u16* __restrict__ pwT)
{
    int bid = blockIdx.x, t = threadIdx.x;
    if (bid < 196) {
        transpose_tile(sw, bigT, 448, 896, bid % 14, bid / 14, t);
    } else if (bid < 784) {
        int l = bid - 196;
        transpose_tile(qkvw, bigT + (size_t)896 * 448, 448, 2688, l % 14, l / 14, t);
    } else {
        int l = bid - 784;
        transpose_tile(pw, pwT, 896, 896, l % 28, l / 28, t);
    }
}

// m1w (1568 blks) | m2w (1568) in one launch
__global__ __launch_bounds__(256) void transpose2(const float* __restrict__ m1w,
    const float* __restrict__ m2w, u16* __restrict__ m1wT, u16* __restrict__ m2wT)
{
    int bid = blockIdx.x, t = threadIdx.x;
    if (bid < 1568) {
        transpose_tile(m1w, m1wT, 896, 3584, bid % 28, bid / 28, t);
    } else {
        int l = bid - 1568;
        transpose_tile(m2w, m2wT, 3584, 896, l % 112, l / 112, t);
    }
}

// zrow zeros + qkv bias -> bf16 + combined [sb|qkvb] fp32, one launch
__global__ __launch_bounds__(256) void prep_small(const float* __restrict__ sb,
    const float* __restrict__ qkvb, u16* __restrict__ zrow,
    u16* __restrict__ qkvbf, float* __restrict__ cbias)
{
    int i = blockIdx.x * 256 + threadIdx.x;
    if (i < 128) zrow[i] = 0;
    if (i < 2688) qkvbf[i] = f2bf(qkvb[i]);
    if (i < 896) cbias[i] = sb[i];
    else if (i < 3584) cbias[i] = qkvb[i - 896];
}

// ---------------- LayerNorm: one wave per pixel (fp32 in, bf16 out) ----------
template<int C>
__global__ __launch_bounds__(256) void ln_kernel(const float* __restrict__ xf,
    const float* __restrict__ g, const float* __restrict__ b,
    u16* __restrict__ out, int npix)
{
    int wid = threadIdx.x >> 6, lane = threadIdx.x & 63;
    int pix = blockIdx.x * 4 + wid;
    if (pix >= npix) return;
    constexpr int J = C / 64;
    float v[J];
    float s = 0.f, s2 = 0.f;
#pragma unroll
    for (int j = 0; j < J; j++) {
        int c = lane + j * 64;
        float t = xf[(size_t)pix * C + c];
        v[j] = t; s += t; s2 += t * t;
    }
#pragma unroll
    for (int off = 32; off; off >>= 1) {
        s  += __shfl_xor(s,  off, 64);
        s2 += __shfl_xor(s2, off, 64);
    }
    float mean = s / C;
    float var = fmaxf(s2 / C - mean * mean, 0.f);
    float rs = rsqrtf(var + 1e-6f);
#pragma unroll
    for (int j = 0; j < J; j++) {
        int c = lane + j * 64;
        float o = (v[j] - mean) * rs * g[c] + b[c];
        out[(size_t)pix * C + c] = f2bf(o);
    }
}

// ---------------- BMx128 MFMA GEMM, BK=32, 2-buffer counted-vmcnt ------------
// Converged config (R4): BM=128 3-4 blk/CU; BM=256/8-phase/3-buffer all
// regressed — cross-block overlap hides the lockstep-phase latency. Mega rate
// (598 TF) is ~98.5% of the 2-phase structural ceiling (m233: 607 TF).
// R12 lesson: nontemporal stores on scalar element stores REGRESS (defeat L2
// write-combining) — plain stores only.
// EPI_MEGA (N=3584 = [skip|q|k|v]): bn<7 skip w/ fused 2x2 pool -> Yf fp32;
// bn 7-13 q w/ fused pool -> qpix bf16 (pixel-pooled layout, same indexing as
// skip); bn 14-20 k -> kimg; bn 21-27 v -> vimg. Attn gathers q/k/v from
// pixel space on the fly with bias fallback for padded taps.
// EPI_PROJ (pixel space): Yf[gm] += val, M=8192.
enum { EPI_GELU = 1, EPI_PROJ = 2, EPI_OUT = 3, EPI_MEGA = 6 };

template<int BM, int EPI, int SWZ>
__global__ __launch_bounds__(256, (BM == 64) ? 6 : 4) void gemm_t(
    const u16* __restrict__ A, const u16* __restrict__ BT,
    const u16* __restrict__ zrow, const float* __restrict__ bias,
    u16* __restrict__ Cb, u16* __restrict__ Cb2, u16* __restrict__ Cb3,
    float* __restrict__ Yf, float* __restrict__ Of,
    int M, int N, int K, int nbn)
{
    constexpr int MI = BM / 32;    // per-wave 16-row frags (wave covers BM/2)
    constexpr int PA = BM / 64;    // A staging units (256 thr x 16B = 4KB each)
    constexpr int ASZ = BM * 32, BSZ = 128 * 32;
    __shared__ __align__(16) u16 As[2][ASZ];
    __shared__ __align__(16) u16 Bs[2][BSZ];

    const int tid = threadIdx.x;
    int bm, bn;
    if (SWZ) {
        int nwg = gridDim.x, orig = blockIdx.x;
        int q = nwg >> 3, r = nwg & 7;
        int xcd = orig & 7, idx = orig >> 3;
        int wg = (xcd < r ? xcd * (q + 1) : r * (q + 1) + (xcd - r) * q) + idx;
        bm = wg / nbn; bn = wg - bm * nbn;
    } else {
        bm = blockIdx.x; bn = blockIdx.y;
    }

    const int wid = tid >> 6, lane = tid & 63;
    const int wm = wid >> 1, wn = wid & 1;
    const int frow = lane & 15, quad = lane >> 4;

    // ---- staging setup (hoisted out of K-loop) ----
    const int srow = tid >> 2, schunk = tid & 3;
    const int ssw = schunk ^ ((srow ^ (srow >> 2)) & 3);   // pre-swizzled chunk

    const u16* gA[PA]; int stA[PA];
#pragma unroll
    for (int p = 0; p < PA; p++) {
        int gm = bm * BM + srow + p * 64;
        int src = (gm < M) ? gm : -1;
        gA[p]  = (src >= 0) ? A + (size_t)src * K + ssw * 8 : zrow + ssw * 8;
        stA[p] = (src >= 0) ? 32 : 0;
    }
    const u16* gB[2];
#pragma unroll
    for (int p = 0; p < 2; p++)
        gB[p] = BT + (size_t)(bn * 128 + srow + p * 64) * K + ssw * 8;

    // ---- fragment-read offsets (constant per thread, swizzled chunk) ----
    const int csw = quad ^ ((frow ^ (frow >> 2)) & 3);
    int offA[MI], offB[4];
#pragma unroll
    for (int mi = 0; mi < MI; mi++)
        offA[mi] = (wm * (BM / 2) + mi * 16 + frow) * 32 + csw * 8;
#pragma unroll
    for (int ni = 0; ni < 4; ni++)
        offB[ni] = (wn * 64 + ni * 16 + frow) * 32 + csw * 8;

    f32x4 acc[MI][4] = {};

    auto stageAdv = [&](int buf) {
#pragma unroll
        for (int p = 0; p < PA; p++) {
            gload16(gA[p], &As[buf][tid * 8 + p * 2048]);
            gA[p] += stA[p];
        }
#pragma unroll
        for (int p = 0; p < 2; p++) {
            gload16(gB[p], &Bs[buf][tid * 8 + p * 2048]);
            gB[p] += 32;
        }
    };
    // loads per stage = PA + 2 (4 for BM=128, 3 for BM=64)
    auto wait_loads = [&]() {
        if constexpr (PA == 2) asm volatile("s_waitcnt vmcnt(4)" ::: "memory");
        else                   asm volatile("s_waitcnt vmcnt(3)" ::: "memory");
    };

    // prologue: tiles 0,1 in flight; drain tile0 only (counted); barrier
    stageAdv(0);
    stageAdv(1);
    wait_loads();
    __builtin_amdgcn_s_barrier();

    int cur = 0;
    const int NK = K / 32;
    for (int kt = 0; kt < NK; kt++) {
        bf16x8 af[MI], bfr[4];
#pragma unroll
        for (int mi = 0; mi < MI; mi++)
            af[mi] = *(const bf16x8*)&As[cur][offA[mi]];
#pragma unroll
        for (int ni = 0; ni < 4; ni++)
            bfr[ni] = *(const bf16x8*)&Bs[cur][offB[ni]];
        asm volatile("s_waitcnt lgkmcnt(0)" ::: "memory");  // our frag reads landed
        __builtin_amdgcn_s_barrier();                       // all readers done
        if (kt + 2 < NK) stageAdv(cur);                     // tile kt+2 -> buf[cur]

#pragma unroll
        for (int mi = 0; mi < MI; mi++)
#pragma unroll
            for (int ni = 0; ni < 4; ni++)
                acc[mi][ni] = __builtin_amdgcn_mfma_f32_16x16x32_bf16(
                    af[mi], bfr[ni], acc[mi][ni], 0, 0, 0);

        if (kt + 1 < NK) {
            // drain tile kt+1's loads (issued a full iteration ago)
            if (kt + 2 < NK) wait_loads();
            else asm volatile("s_waitcnt vmcnt(0)" ::: "memory");
            __builtin_amdgcn_s_barrier();
        }
        cur ^= 1;
    }

    // ---------------- epilogues ----------------
    if (EPI == EPI_MEGA && bn < 14) {
        // BM=128: block = 2 image rows (64px). wm=0 holds gh=2*oy,
        // wm=1 holds gh=2*oy+1; gw pairs live in acc i-pairs. Both thirds
        // write pixel-pooled layout: skip -> Yf fp32, q -> qpix bf16.
        __syncthreads();                       // all frag reads done; reuse As
        float* Pool = (float*)As;              // 32 x 128 fp32 = 16KB
        if (wm == 1) {
#pragma unroll
            for (int mi = 0; mi < MI; mi++)
#pragma unroll
            for (int ni = 0; ni < 4; ni++) {
                int ox0 = mi * 8 + quad * 2;
                int gnl = wn * 64 + ni * 16 + frow;
                Pool[(ox0 + 0) * 128 + gnl] = fmaxf(acc[mi][ni][0], acc[mi][ni][1]);
                Pool[(ox0 + 1) * 128 + gnl] = fmaxf(acc[mi][ni][2], acc[mi][ni][3]);
            }
        }
        __syncthreads();
        if (wm == 0) {
            int b = bm >> 5, oy = bm & 31;
#pragma unroll
            for (int mi = 0; mi < MI; mi++)
#pragma unroll
            for (int ni = 0; ni < 4; ni++) {
                int ox0 = mi * 8 + quad * 2;
                int gnl = wn * 64 + ni * 16 + frow;
                int gn = bn * 128 + gnl;
                float bv = bias[gn];
                float v0 = fmaxf(fmaxf(acc[mi][ni][0], acc[mi][ni][1]),
                                 Pool[(ox0 + 0) * 128 + gnl]) + bv;
                float v1 = fmaxf(fmaxf(acc[mi][ni][2], acc[mi][ni][3]),
                                 Pool[(ox0 + 1) * 128 + gnl]) + bv;
                size_t pix = (size_t)((b * 32 + oy) * 32 + ox0);
                if (bn < 7) {
                    Yf[pix * 896 + gn] = v0;
                    Yf[(pix + 1) * 896 + gn] = v1;
                } else {
                    int col = gn - 896;
                    Cb3[pix * 896 + col] = f2bf(v0);
                    Cb3[(pix + 1) * 896 + col] = f2bf(v1);
                }
            }
        }
        return;
    }

    // element-wise epilogues: D lane layout col = lane&15, row = quad*4 + i
#pragma unroll
    for (int mi = 0; mi < MI; mi++)
#pragma unroll
    for (int ni = 0; ni < 4; ni++)
#pragma unroll
    for (int i = 0; i < 4; i++) {
        int gm = bm * BM + wm * (BM / 2) + mi * 16 + quad * 4 + i;
        int gn = bn * 128 + wn * 64 + ni * 16 + frow;
        if (gm >= M) continue;
        float val = acc[mi][ni][i] + bias[gn];
        if (EPI == EPI_MEGA) {
            int third = gn / 896;            // 2 => k, 3 => v (bn>=14 here)
            int col = gn - third * 896;
            u16* dst = (third == 2) ? Cb : Cb2;
            dst[(size_t)gm * 896 + col] = f2bf(val);
        } else if (EPI == EPI_GELU) {
            float ge = 0.5f * val * (1.0f + erff(val * 0.70710678118654752f));
            Cb[(size_t)gm * N + gn] = f2bf(ge);
        } else if (EPI == EPI_PROJ) {
            Yf[(size_t)gm * 896 + gn] += val;   // pixel space: y = shortcut + xo
        } else { // EPI_OUT: final output FP32
            Of[(size_t)gm * 896 + gn] = val + Yf[(size_t)gm * 896 + gn];
        }
    }
}

// ---------------- MFMA attention: one block per (window, head) ---------------
// Q/K/V all gathered from pixel space on the fly; padded taps read the bf16
// qkv bias vector (q bias = qkvbf+0, k = +896, v = +1792).
// Output ao written in PIXEL space (valid q rows only; windows disjoint).
__global__ __launch_bounds__(256) void attn_mfma(const u16* __restrict__ qpix,
    const u16* __restrict__ kimg, const u16* __restrict__ vimg,
    const u16* __restrict__ qkvbf, u16* __restrict__ ao)
{
    __shared__ __align__(16) u16 Ps[64][232];
    __shared__ __align__(16) u16 KV[208 * 72];

    const float SCALE = 0.13363062095621219f;   // 56^-0.5
    const int w = blockIdx.x >> 4, h = blockIdx.x & 15;
    const int tid = threadIdx.x;
    const int wid = tid >> 6, lane = tid & 63;
    const int n16 = lane & 15, quad = lane >> 4;

    const int b = w / 25, wh = (w / 5) % 5, ww = w % 5;
    const int ghb = wh * 14, gwb = ww * 14;

    for (int idx = tid; idx < 64 * 232 / 8; idx += 256)
        *(uint4*)&Ps[0][idx * 8] = make_uint4(0u, 0u, 0u, 0u);
    for (int idx = tid; idx < 208 * 9; idx += 256) {
        int n = idx / 9, kc = (idx % 9) * 8;
        uint4 val = make_uint4(0u, 0u, 0u, 0u);
        if (n < 196 && kc < 56) {
            int ty = n / 14, tx = n - 14 * ty;
            int gh = ghb + ty, gw = gwb + tx;
            const u16* src = (gh < 64 && gw < 64)
                ? kimg + (size_t)((b * 64 + gh) * 64 + gw) * 896 + h * 56 + kc
                : qkvbf + 896 + h * 56 + kc;
            val = *(const uint4*)src;
        }
        *(uint4*)&KV[n * 72 + kc] = val;
    }
    bf16x8 qf[2];
    {
        int m = 16 * wid + n16;
        int mm = (m < 49) ? m : 48;
        int qy = mm / 7, qx = mm - 7 * qy;
        int oy = wh * 7 + qy, ox = ww * 7 + qx;
        const u16* src = (oy < 32 && ox < 32)
            ? qpix + (size_t)((b * 32 + oy) * 32 + ox) * 896 + h * 56
            : qkvbf + h * 56;
#pragma unroll
        for (int ks = 0; ks < 2; ks++) {
            int kk = ks * 32 + quad * 8;
            uint4 v = make_uint4(0u, 0u, 0u, 0u);
            if (kk < 56) v = *(const uint4*)(src + kk);
            qf[ks] = __builtin_bit_cast(bf16x8, v);
        }
    }
    __syncthreads();

    f32x4 S[13] = {};
#pragma unroll
    for (int nt = 0; nt < 13; nt++) {
#pragma unroll
        for (int ks = 0; ks < 2; ks++) {
            bf16x8 bf = *(const bf16x8*)&KV[(nt * 16 + n16) * 72 + ks * 32 + quad * 8];
            S[nt] = __builtin_amdgcn_mfma_f32_16x16x32_bf16(qf[ks], bf, S[nt], 0, 0, 0);
        }
    }
#pragma unroll
    for (int i = 0; i < 4; i++) {
        float mx = -3.0e38f;
#pragma unroll
        for (int nt = 0; nt < 13; nt++) {
            float v = S[nt][i] * SCALE;
            S[nt][i] = v;
            if (nt < 12 || n16 < 4) mx = fmaxf(mx, v);
        }
        mx = fmaxf(mx, __shfl_xor(mx, 1, 64));
        mx = fmaxf(mx, __shfl_xor(mx, 2, 64));
        mx = fmaxf(mx, __shfl_xor(mx, 4, 64));
        mx = fmaxf(mx, __shfl_xor(mx, 8, 64));
        float sm = 0.f;
#pragma unroll
        for (int nt = 0; nt < 13; nt++) {
            float e = (nt < 12 || n16 < 4) ? __expf(S[nt][i] - mx) : 0.f;
            S[nt][i] = e;
            sm += e;
        }
        sm += __shfl_xor(sm, 1, 64);
        sm += __shfl_xor(sm, 2, 64);
        sm += __shfl_xor(sm, 4, 64);
        sm += __shfl_xor(sm, 8, 64);
        float inv = 1.f / sm;
#pragma unroll
        for (int nt = 0; nt < 13; nt++) S[nt][i] *= inv;
    }
    __syncthreads();

#pragma unroll
    for (int nt = 0; nt < 13; nt++)
#pragma unroll
        for (int i = 0; i < 4; i++)
            Ps[16 * wid + 4 * quad + i][16 * nt + n16] = f2bf(S[nt][i]);

    // V-transpose staging: uint4 loads of pixel pairs, packed b32 LDS writes
    u16 (*Vs)[232] = reinterpret_cast<u16(*)[232]>(KV);
    for (int idx = tid; idx < 98 * 7; idx += 256) {
        int j2 = idx / 7, dc = idx % 7;
        int j = 2 * j2;
        int ty = j / 14, tx = j - 14 * ty;        // tx even <= 12
        int gh = ghb + ty, gw = gwb + tx;
        int off = h * 56 + dc * 8;
        const u16* p0 = (gh < 64 && gw < 64)
            ? vimg + (size_t)((b * 64 + gh) * 64 + gw) * 896 + off
            : qkvbf + 1792 + off;
        const u16* p1 = (gh < 64 && gw + 1 < 64)
            ? vimg + (size_t)((b * 64 + gh) * 64 + gw + 1) * 896 + off
            : qkvbf + 1792 + off;
        uint4 a = *(const uint4*)p0;
        uint4 bb = *(const uint4*)p1;
        u16 ua[8], ub[8];
        *(uint4*)ua = a; *(uint4*)ub = bb;
#pragma unroll
        for (int i = 0; i < 8; i++) {
            unsigned pair = (unsigned)ua[i] | ((unsigned)ub[i] << 16);
            *(unsigned*)&Vs[dc * 8 + i][j] = pair;
        }
    }
    for (int idx = tid; idx < 64 * 14; idx += 256) {
        int d = idx / 14, c = idx % 14;
        *(unsigned*)&Vs[d][196 + 2 * c] = 0u;
    }
    __syncthreads();

    f32x4 O[4] = {};
#pragma unroll
    for (int ks = 0; ks < 7; ks++) {
        bf16x8 a = *(const bf16x8*)&Ps[16 * wid + n16][ks * 32 + quad * 8];
#pragma unroll
        for (int nt = 0; nt < 4; nt++) {
            bf16x8 b2 = *(const bf16x8*)&Vs[16 * nt + n16][ks * 32 + quad * 8];
            O[nt] = __builtin_amdgcn_mfma_f32_16x16x32_bf16(a, b2, O[nt], 0, 0, 0);
        }
    }
#pragma unroll
    for (int nt = 0; nt < 4; nt++)
#pragma unroll
        for (int i = 0; i < 4; i++) {
            int m = 16 * wid + 4 * quad + i;
            int d = 16 * nt + n16;
            if (m < 49 && d < 56) {
                int qy = m / 7, qx = m - 7 * qy;
                int oy = wh * 7 + qy, ox = ww * 7 + qx;
                if (oy < 32 && ox < 32) {
                    size_t pix = (size_t)((b * 32 + oy) * 32 + ox);
                    ao[pix * 896 + h * 56 + d] = f2bf(O[nt][i]);
                }
            }
        }
}

extern "C" void kernel_launch(void* const* d_in, const int* in_sizes, int n_in,
                              void* d_out, int out_size, void* d_ws, size_t ws_size,
                              hipStream_t stream)
{
    const float* x    = (const float*)d_in[0];
    const float* ln1g = (const float*)d_in[1];
    const float* ln1b = (const float*)d_in[2];
    const float* qkvw = (const float*)d_in[3];
    const float* qkvb = (const float*)d_in[4];
    const float* pw   = (const float*)d_in[5];
    const float* pb   = (const float*)d_in[6];
    const float* sw   = (const float*)d_in[7];
    const float* sb   = (const float*)d_in[8];
    const float* ln2g = (const float*)d_in[9];
    const float* ln2b = (const float*)d_in[10];
    const float* m1w  = (const float*)d_in[11];
    const float* m1b  = (const float*)d_in[12];
    const float* m2w  = (const float*)d_in[13];
    const float* m2b  = (const float*)d_in[14];

    char* ws = (char*)d_ws;
    // ws layout, lifetime-aliased. Peak ~216.1 MB.
    u16*   kimg = (u16*)(ws + 0);             // 58,720,256 B; after attn: m1
    u16*   vimg = (u16*)(ws + 58720256);      // 58,720,256 B; after attn: m1wT/m2wT
    u16*   hn   = (u16*)(ws + 117440512);     // 29,360,128 B; later hn2
    float* Yf   = (float*)(ws + 146800640);   // 29,360,128 B (8192*896 fp32)
    u16*   qpix = (u16*)(ws + 176160768);     // 14,680,064 B (8192x896 pooled px)
    u16*   ao   = (u16*)(ws + 193722368);     // 14,680,064 B (8192x896 pixel)
    u16*   bigT = (u16*)(ws + 211283968);     //  3,211,264 B ([sw|qkv]^T 3584x448)
    u16*   pwT  = (u16*)(ws + 214495232);     //  1,605,632 B (896x896)
    u16*   qkvbf= (u16*)(ws + 216100864);     //      5,376 B (2688 bf16)
    float* cbias= (float*)(ws + 216106240);   //     14,336 B (3584 fp32)
    u16*   zrow = (u16*)(ws + 216120576);     //        256 B zeros
    u16*   m1   = kimg;                       // 58,720,256 B (8192x3584)
    u16*   hn2  = hn;
    u16*   m1wT = vimg;                       // 6,422,528 B (3584x896)
    u16*   m2wT = (u16*)(ws + 58720256 + 6422528); // 6,422,528 B (896x3584)
    float* outf = (float*)d_out;

    // 0. prep: zeros + biases (1 launch), pre-transposes (1 launch)
    prep_small<<<14, 256, 0, stream>>>(sb, qkvb, zrow, qkvbf, cbias);
    transpose3<<<1176, 256, 0, stream>>>(sw, qkvw, pw, bigT, pwT);
    // 1. hn = LN1(x)
    ln_kernel<448><<<8192, 256, 0, stream>>>(x, ln1g, ln1b, hn, 32768);
    // 2-7. MEGA: [shortcut-pool | q-pool | k | v] = hn @ [sw|Wqkv] + [sb|bqkv]
    gemm_t<128, EPI_MEGA, 1><<<256 * 28, 256, 0, stream>>>(
        hn, bigT, zrow, cbias, kimg, vimg, qpix, Yf, nullptr,
        32768, 3584, 448, 28);
    // 8. attention (MFMA; all operands gathered from pixel space)
    attn_mfma<<<3200, 256, 0, stream>>>(qpix, kimg, vimg, qkvbf, ao);
    // 8b. mlp weight transposes into dead vimg region (1 launch)
    transpose2<<<3136, 256, 0, stream>>>(m1w, m2w, m1wT, m2wT);
    // 9. y += ao @ proj_w + proj_b   (pixel space, M=8192)
    gemm_t<64, EPI_PROJ, 1><<<128 * 7, 256, 0, stream>>>(
        ao, pwT, zrow, pb, nullptr, nullptr, nullptr, Yf, nullptr,
        8192, 896, 896, 7);
    // 10. hn2 = LN2(y)
    ln_kernel<896><<<2048, 256, 0, stream>>>(Yf, ln2g, ln2b, hn2, 8192);
    // 11. m1 = gelu(hn2 @ mlp1_w + mlp1_b)   (natural order: B large)
    gemm_t<128, EPI_GELU, 0><<<dim3(64, 28), 256, 0, stream>>>(
        hn2, m1wT, zrow, m1b, m1, nullptr, nullptr, nullptr, nullptr,
        8192, 3584, 896, 28);
    // 12. out = y + m1 @ mlp2_w + mlp2_b   (fp32 store)
    gemm_t<64, EPI_OUT, 0><<<dim3(128, 7), 256, 0, stream>>>(
        m1, m2wT, zrow, m2b, nullptr, nullptr, nullptr, Yf, outf,
        8192, 896, 3584, 7);
}